// Round 2
// baseline (11939.565 us; speedup 1.0000x reference)
//
#include <hip/hip_runtime.h>
#include <math.h>

#define D_    1024
#define B_    2
#define N_    512
#define SEG_  128
#define NSEG_ 4
#define NPT_  16
#define T_    272
#define NH_   16
#define HD_   64
#define W_    128
#define V_    32000

#define THETA_ 0.1f
#define ETA_   0.9f
#define PDEC_  0.99f
#define EPSN_  1e-6f

// ---------------- workspace layout (float offsets) ----------------
static const size_t XEMB = 0;                       // [B,N,D]
static const size_t OUTS = XEMB + (size_t)B_*N_*D_; // [B,N,D]
static const size_t PW1  = OUTS + (size_t)B_*N_*D_; // [B,1024,128]
static const size_t PB1  = PW1  + (size_t)B_*D_*W_; // [B,128]
static const size_t PW2T = PB1  + (size_t)B_*W_;    // [B,1024,128]  (W2 transposed: [j][h])
static const size_t PB2  = PW2T + (size_t)B_*D_*W_; // [B,1024]
static const size_t MOM  = PB2  + (size_t)B_*D_;    // momentum block (contiguous, memset 0)
static const size_t MW1  = MOM;
static const size_t MB1  = MW1  + (size_t)B_*D_*W_;
static const size_t MW2T = MB1  + (size_t)B_*W_;
static const size_t MB2  = MW2T + (size_t)B_*D_*W_;
static const size_t MOMSZ = (size_t)B_*(D_*W_ + W_ + D_*W_ + D_);
static const size_t Q1   = MOM  + MOMSZ;            // [B,128,1024]
static const size_t AH   = Q1   + (size_t)B_*SEG_*D_; // [B,128,128]
static const size_t HBUF = AH   + (size_t)B_*SEG_*W_; // [B,128,1024]
static const size_t COMB = HBUF + (size_t)B_*SEG_*D_; // [B,272,1024]
static const size_t QKV  = COMB + (size_t)B_*T_*D_;   // [B,272,3072]
static const size_t ATTN = QKV  + (size_t)B_*T_*3*D_; // [B,128,1024]
static const size_t SEGO = ATTN + (size_t)B_*SEG_*D_; // [B,128,1024]
static const size_t KM   = SEGO + (size_t)B_*SEG_*D_; // [B,128,1024]
static const size_t VM   = KM   + (size_t)B_*SEG_*D_; // [B,128,1024]
static const size_t MEMO = VM   + (size_t)B_*SEG_*D_; // [B,128,1024]
static const size_t Z1P  = MEMO + (size_t)B_*SEG_*D_; // [B,64,128]
static const size_t DZ1P = Z1P  + (size_t)B_*64*W_;   // [B,64,128]
static const size_t A1G  = DZ1P + (size_t)B_*64*W_;   // [2,B,128] parity
static const size_t Z1FG = A1G  + (size_t)2*B_*W_;    // [B,128]
static const size_t EG   = Z1FG + (size_t)B_*W_;      // [B,1024]
static const size_t WSEND = EG + (size_t)B_*D_;

__device__ __forceinline__ float sigf(float x) { return 1.f/(1.f+expf(-x)); }

// ---------------- generic tiled fp32 GEMM ----------------
// C[M,N] = A[M,K] @ B (+bias); BT: B stored [N,K] row-major; SILU epilogue option.
// lda=K, ldb=N (or K if BT), ldc=N. batch via grid.z with strides.
template<int BT, int SILU>
__global__ __launch_bounds__(256) void k_gemm(
    const float* __restrict__ A, const float* __restrict__ Bm,
    const float* __restrict__ bias, float* __restrict__ C,
    int M, int N, int K, long sA, long sB, long sC, long sBias)
{
  __shared__ float As[16][68];
  __shared__ float Bs[16][68];
  int bz = blockIdx.z;
  A += bz*sA; Bm += bz*sB; C += bz*sC; bias += bz*sBias;
  int n0 = blockIdx.x*64, m0 = blockIdx.y*64;
  int tid = threadIdx.x;
  int tx = tid & 15, ty = tid >> 4;
  int r  = tid >> 2;          // 0..63
  int kq = (tid & 3) * 4;     // 0,4,8,12
  float acc[4][4] = {};
  for (int k0 = 0; k0 < K; k0 += 16) {
    { // A tile -> As[kk][m]
      int row = m0 + r;
      float4 v = make_float4(0.f,0.f,0.f,0.f);
      if (row < M) v = *(const float4*)(A + (long)row*K + k0 + kq);
      As[kq+0][r]=v.x; As[kq+1][r]=v.y; As[kq+2][r]=v.z; As[kq+3][r]=v.w;
    }
    if (BT) { // B[N,K] -> Bs[kk][n]
      int row = n0 + r;
      float4 v = *(const float4*)(Bm + (long)row*K + k0 + kq);
      Bs[kq+0][r]=v.x; Bs[kq+1][r]=v.y; Bs[kq+2][r]=v.z; Bs[kq+3][r]=v.w;
    } else {  // B[K,N] -> Bs[kk][n]
      int c = tid & 63, r4 = tid >> 6;
      #pragma unroll
      for (int p = 0; p < 4; p++) {
        int kk = r4 + p*4;
        Bs[kk][c] = Bm[(long)(k0+kk)*N + n0 + c];
      }
    }
    __syncthreads();
    #pragma unroll
    for (int kk = 0; kk < 16; kk++) {
      float av[4], bv[4];
      #pragma unroll
      for (int i=0;i<4;i++) av[i] = As[kk][ty*4+i];
      #pragma unroll
      for (int j=0;j<4;j++) bv[j] = Bs[kk][tx*4+j];
      #pragma unroll
      for (int i=0;i<4;i++)
        #pragma unroll
        for (int j=0;j<4;j++)
          acc[i][j] = fmaf(av[i], bv[j], acc[i][j]);
    }
    __syncthreads();
  }
  #pragma unroll
  for (int i=0;i<4;i++) {
    int row = m0 + ty*4 + i;
    if (row >= M) continue;
    #pragma unroll
    for (int j=0;j<4;j++) {
      int col = n0 + tx*4 + j;
      float v = acc[i][j] + bias[col];
      if (SILU) v = v * sigf(v);
      C[(long)row*N + col] = v;
    }
  }
}

// ---------------- small kernels ----------------
__global__ void k_embed(const int* __restrict__ x, const float* __restrict__ emb,
                        float* __restrict__ xe)
{
  int row = blockIdx.x, tid = threadIdx.x;
  int idx = x[row];
  float4 v = *(const float4*)(emb + (long)idx*D_ + tid*4);
  *(float4*)(xe + (long)row*D_ + tid*4) = v;
}

#define PER_ 263296L // 131072 + 128 + 131072 + 1024
__global__ void k_init(const float* __restrict__ mW1in, const float* __restrict__ mb1in,
                       const float* __restrict__ mW2in, const float* __restrict__ mb2in,
                       float* __restrict__ pW1, float* __restrict__ pb1,
                       float* __restrict__ pW2T, float* __restrict__ pb2)
{
  long g = (long)blockIdx.x*256 + threadIdx.x;
  if (g >= 2*PER_) return;
  int b = (int)(g / PER_);
  long rr = g % PER_;
  if (rr < 131072)       pW1[(long)b*131072 + rr] = mW1in[rr];
  else if (rr < 131200)  pb1[b*W_ + (rr-131072)] = mb1in[rr-131072];
  else if (rr < 262272) { long l = rr-131200; int j=(int)(l>>7), h=(int)(l&127);
                          pW2T[(long)b*131072 + l] = mW2in[(long)h*D_ + j]; }
  else                   pb2[b*D_ + (rr-262272)] = mb2in[rr-262272];
}

__global__ __launch_bounds__(256) void k_l2n(float* __restrict__ X)
{
  long row = blockIdx.x;
  float* p = X + row*D_;
  int tid = threadIdx.x;
  float4 v = *(float4*)(p + tid*4);
  float ss = v.x*v.x + v.y*v.y + v.z*v.z + v.w*v.w;
  for (int o=32;o;o>>=1) ss += __shfl_xor(ss,o);
  __shared__ float wsum[4];
  if ((tid&63)==0) wsum[tid>>6] = ss;
  __syncthreads();
  float tot = wsum[0]+wsum[1]+wsum[2]+wsum[3];
  float sc = 1.f/(sqrtf(tot)+EPSN_);
  v.x*=sc; v.y*=sc; v.z*=sc; v.w*=sc;
  *(float4*)(p + tid*4) = v;
}

__global__ void k_concat(const float* __restrict__ pers, const float* __restrict__ h,
                         const float* __restrict__ xemb, int s, float* __restrict__ comb)
{
  int row = blockIdx.x, b = blockIdx.y, tid = threadIdx.x;
  const float* src;
  if (row < NPT_)            src = pers + (long)row*D_;
  else if (row < NPT_+SEG_)  src = h    + ((long)b*SEG_ + (row-NPT_))*D_;
  else                       src = xemb + ((long)b*N_ + s*SEG_ + (row-NPT_-SEG_))*D_;
  float4 v = *(const float4*)(src + tid*4);
  *(float4*)(comb + ((long)b*T_ + row)*D_ + tid*4) = v;
}

// attention: only last SEG_ query rows. grid (8 qtiles, 16 heads, 2 batch), 256 thr
__global__ __launch_bounds__(256) void k_attn(const float* __restrict__ qkv,
                                              float* __restrict__ outp)
{
  __shared__ float sQ[16][68];
  __shared__ float sKV[64][68];
  __shared__ float sS[16][273];
  int qt = blockIdx.x, head = blockIdx.y, b = blockIdx.z;
  int tid = threadIdx.x;
  const float* base = qkv + (long)b*T_*3*D_;
  int qoff = head*HD_, koff = D_ + head*HD_, voff = 2*D_ + head*HD_;
  int qrow0 = NPT_ + SEG_ + qt*16;
  { // Q tile
    int rr = tid>>4, c4 = (tid&15)*4;
    float4 v = *(const float4*)(base + (long)(qrow0+rr)*3*D_ + qoff + c4);
    sQ[rr][c4]=v.x; sQ[rr][c4+1]=v.y; sQ[rr][c4+2]=v.z; sQ[rr][c4+3]=v.w;
  }
  __syncthreads();
  // scores
  for (int j0 = 0; j0 < T_; j0 += 64) {
    int chunk = min(64, T_ - j0);
    {
      int jj = tid>>2, cq = (tid&3)*16;
      if (jj < chunk) {
        #pragma unroll
        for (int q4=0;q4<4;q4++) {
          float4 v = *(const float4*)(base + (long)(j0+jj)*3*D_ + koff + cq + q4*4);
          sKV[jj][cq+q4*4]=v.x; sKV[jj][cq+q4*4+1]=v.y; sKV[jj][cq+q4*4+2]=v.z; sKV[jj][cq+q4*4+3]=v.w;
        }
      }
    }
    __syncthreads();
    int rr = tid>>4, jj0 = tid&15;
    #pragma unroll
    for (int p=0;p<4;p++) {
      int jj = jj0 + p*16;
      if (jj < chunk) {
        float s = 0.f;
        #pragma unroll 8
        for (int c=0;c<HD_;c++) s = fmaf(sQ[rr][c], sKV[jj][c], s);
        s *= 0.125f;
        int jg = j0 + jj, qg = qrow0 + rr;
        if (jg > qg) s = -3.0e38f;
        sS[rr][jg] = s;
      }
    }
    __syncthreads();
  }
  // softmax per row (16 threads/row)
  {
    int rr = tid>>4, l16 = tid&15;
    float m = -3.4e38f;
    for (int j=l16; j<T_; j+=16) m = fmaxf(m, sS[rr][j]);
    for (int o=8;o;o>>=1) m = fmaxf(m, __shfl_xor(m,o));
    float sum = 0.f;
    for (int j=l16; j<T_; j+=16) { float e = expf(sS[rr][j]-m); sS[rr][j] = e; sum += e; }
    for (int o=8;o;o>>=1) sum += __shfl_xor(sum,o);
    float inv = 1.f/sum;
    for (int j=l16; j<T_; j+=16) sS[rr][j] *= inv;
  }
  __syncthreads();
  // out = P @ V
  float acc[4] = {0.f,0.f,0.f,0.f};
  int rr = tid>>4, c4 = (tid&15)*4;
  for (int j0 = 0; j0 < T_; j0 += 64) {
    int chunk = min(64, T_ - j0);
    {
      int jj = tid>>2, cq = (tid&3)*16;
      if (jj < chunk) {
        #pragma unroll
        for (int q4=0;q4<4;q4++) {
          float4 v = *(const float4*)(base + (long)(j0+jj)*3*D_ + voff + cq + q4*4);
          sKV[jj][cq+q4*4]=v.x; sKV[jj][cq+q4*4+1]=v.y; sKV[jj][cq+q4*4+2]=v.z; sKV[jj][cq+q4*4+3]=v.w;
        }
      }
    }
    __syncthreads();
    for (int jj=0; jj<chunk; jj++) {
      float p = sS[rr][j0+jj];
      #pragma unroll
      for (int i=0;i<4;i++) acc[i] = fmaf(p, sKV[jj][c4+i], acc[i]);
    }
    __syncthreads();
  }
  float4 o4 = make_float4(acc[0],acc[1],acc[2],acc[3]);
  *(float4*)(outp + ((long)(b*SEG_) + qt*16 + rr)*D_ + head*HD_ + c4) = o4;
}

// ---------------- token-scan kernels (2 per token, 64 blocks each) ----------------
// tokA: reduce dz1 partials of t-1, update W1/b1 slices, emit z1 partials of t
__global__ __launch_bounds__(256) void k_tokA(
    float* __restrict__ pW1, float* __restrict__ pb1,
    float* __restrict__ mW1, float* __restrict__ mb1,
    const float* __restrict__ Km, const float* __restrict__ z1fg,
    const float* __restrict__ dz1p, float* __restrict__ z1p, int t)
{
  __shared__ float s_dz1[B_][W_];
  int blk = blockIdx.x, tid = threadIdx.x;
  int b = tid>>7, h = tid&127;
  if (t > 0) {
    float s = 0.f;
    for (int k2=0;k2<64;k2++) s += dz1p[((long)b*64 + k2)*W_ + h];
    float z = z1fg[b*W_ + h];
    float sg = sigf(z);
    s_dz1[b][h] = s * sg * (1.f + z*(1.f - sg));
    __syncthreads();
    #pragma unroll
    for (int i=0;i<16;i++) {
      int lin = tid + i*256;
      int hb = lin & 127, dd = (lin>>7)&15, bb2 = lin>>11;
      int d = blk*16 + dd;
      long idx = (long)bb2*131072 + (long)d*W_ + hb;
      float kv = Km[((long)bb2*SEG_ + (t-1))*D_ + d];
      float m = ETA_*mW1[idx] - THETA_*kv*s_dz1[bb2][hb];
      mW1[idx] = m;
      pW1[idx] = PDEC_*pW1[idx] + m;
    }
    if (blk == 0) {
      float m = ETA_*mb1[b*W_+h] - THETA_*s_dz1[b][h];
      mb1[b*W_+h] = m;
      pb1[b*W_+h] = PDEC_*pb1[b*W_+h] + m;
    }
    __syncthreads();
  }
  if (t < SEG_) {
    float acc = 0.f;
    #pragma unroll
    for (int dd=0;dd<16;dd++) {
      int d = blk*16 + dd;
      acc = fmaf(Km[((long)b*SEG_ + t)*D_ + d], pW1[(long)b*131072 + (long)d*W_ + h], acc);
    }
    z1p[((long)b*64 + blk)*W_ + h] = acc;
  }
}

// tokB: update W2T/b2 slices (from t-1), reduce z1 -> a1, compute z2/e, dz1 partials
__global__ __launch_bounds__(256) void k_tokB(
    float* __restrict__ pW2T, float* __restrict__ pb2,
    float* __restrict__ mW2T, float* __restrict__ mb2,
    const float* __restrict__ pb1,
    const float* __restrict__ Vm, const float* __restrict__ z1p,
    float* __restrict__ dz1p, float* __restrict__ a1g, float* __restrict__ z1fg,
    float* __restrict__ eg, int t)
{
  __shared__ float sW[B_][16][W_];
  __shared__ float s_a1[B_][W_];
  __shared__ float s_a1o[B_][W_];
  __shared__ float s_eo[B_][16];
  __shared__ float s_e[B_][16];
  int blk = blockIdx.x, tid = threadIdx.x;
  int b = tid>>7, h = tid&127;
  if (t > 0) {
    s_a1o[b][h] = a1g[((t-1)&1)*B_*W_ + b*W_ + h];
    if (tid < B_*16) {
      int bb2 = tid>>4, jj = tid&15;
      s_eo[bb2][jj] = eg[bb2*D_ + blk*16 + jj];
    }
    __syncthreads();
  }
  #pragma unroll
  for (int i=0;i<16;i++) {
    int lin = tid + i*256;
    int hb = lin&127, jj = (lin>>7)&15, bb2 = lin>>11;
    long idx = (long)bb2*131072 + (long)(blk*16+jj)*W_ + hb;
    float w;
    if (t > 0) {
      float m = ETA_*mW2T[idx] - 0.2f*s_eo[bb2][jj]*s_a1o[bb2][hb];
      mW2T[idx] = m;
      w = PDEC_*pW2T[idx] + m;
      pW2T[idx] = w;
    } else w = pW2T[idx];
    sW[bb2][jj][hb] = w;
  }
  if (t > 0 && tid < B_*16) {
    int bb2 = tid>>4, jj = tid&15;
    long idx = bb2*D_ + blk*16 + jj;
    float m = ETA_*mb2[idx] - 0.2f*s_eo[bb2][jj];
    mb2[idx] = m;
    pb2[idx] = PDEC_*pb2[idx] + m;
  }
  if (t == SEG_) return;
  __syncthreads();
  // z1 reduce + a1
  float s = 0.f;
  for (int k2=0;k2<64;k2++) s += z1p[((long)b*64 + k2)*W_ + h];
  float z1f = s + pb1[b*W_ + h];
  float a1 = z1f * sigf(z1f);
  s_a1[b][h] = a1;
  if (blk == 0) {
    z1fg[b*W_ + h] = z1f;
    a1g[(t&1)*B_*W_ + b*W_ + h] = a1;
  }
  __syncthreads();
  // z2/e rows (32 rows x 8 lanes)
  {
    int rowi = tid>>3, l8 = tid&7;
    int bb2 = rowi>>4, jj = rowi&15;
    float acc = 0.f;
    for (int hh=l8; hh<W_; hh+=8) acc = fmaf(s_a1[bb2][hh], sW[bb2][jj][hh], acc);
    acc += __shfl_xor(acc,4); acc += __shfl_xor(acc,2); acc += __shfl_xor(acc,1);
    if (l8 == 0) {
      int j = blk*16 + jj;
      float e = acc + pb2[bb2*D_ + j] - Vm[((long)bb2*SEG_ + t)*D_ + j];
      s_e[bb2][jj] = e;
      eg[bb2*D_ + j] = e;
    }
  }
  __syncthreads();
  // dz1 partials
  {
    float acc = 0.f;
    #pragma unroll
    for (int jj=0;jj<16;jj++) acc = fmaf(2.f*s_e[b][jj], sW[b][jj][h], acc);
    dz1p[((long)b*64 + blk)*W_ + h] = acc;
  }
}

__global__ void k_mul(const float* __restrict__ so, const float* __restrict__ mo,
                      float* __restrict__ outs, int s)
{
  int l = blockIdx.x, b = blockIdx.y, tid = threadIdx.x;
  long src = ((long)b*SEG_ + l)*D_ + tid*4;
  float4 a = *(const float4*)(so + src);
  float4 c = *(const float4*)(mo + src);
  a.x*=c.x; a.y*=c.y; a.z*=c.z; a.w*=c.w;
  *(float4*)(outs + ((long)b*N_ + s*SEG_ + l)*D_ + tid*4) = a;
}

// ---------------- host launcher ----------------
static inline void gemm(const float* A, const float* Bm, const float* bias, float* C,
                        int M, int N, int K, long sA, long sB, long sC, long sBias,
                        int batch, int bt, int silu_, hipStream_t st)
{
  dim3 g(N/64, (M+63)/64, batch), blk(256);
  if (!bt && !silu_) k_gemm<0,0><<<g,blk,0,st>>>(A,Bm,bias,C,M,N,K,sA,sB,sC,sBias);
  else if (!bt && silu_) k_gemm<0,1><<<g,blk,0,st>>>(A,Bm,bias,C,M,N,K,sA,sB,sC,sBias);
  else k_gemm<1,0><<<g,blk,0,st>>>(A,Bm,bias,C,M,N,K,sA,sB,sC,sBias);
}

extern "C" void kernel_launch(void* const* d_in, const int* in_sizes, int n_in,
                              void* d_out, int out_size, void* d_ws, size_t ws_size,
                              hipStream_t stream)
{
  (void)in_sizes; (void)n_in; (void)out_size; (void)ws_size;
  const int*   x     = (const int*)  d_in[0];
  const float* emb   = (const float*)d_in[1];
  const float* pers  = (const float*)d_in[2];
  const float* Wq    = (const float*)d_in[3];
  const float* bq    = (const float*)d_in[4];
  const float* Wk    = (const float*)d_in[5];
  const float* bk    = (const float*)d_in[6];
  const float* Wv    = (const float*)d_in[7];
  const float* bv    = (const float*)d_in[8];
  const float* aiw   = (const float*)d_in[9];
  const float* aib   = (const float*)d_in[10];
  const float* aow   = (const float*)d_in[11];
  const float* aob   = (const float*)d_in[12];
  const float* mW1in = (const float*)d_in[13];
  const float* mb1in = (const float*)d_in[14];
  const float* mW2in = (const float*)d_in[15];
  const float* mb2in = (const float*)d_in[16];
  const float* headw = (const float*)d_in[17];
  const float* headb = (const float*)d_in[18];
  float* out = (float*)d_out;
  float* ws  = (float*)d_ws;

  // init: momentum = 0, params = broadcast of inputs (W2 transposed)
  hipMemsetAsync(ws + MOM, 0, MOMSZ*sizeof(float), stream);
  k_embed<<<dim3(B_*N_), dim3(256), 0, stream>>>(x, emb, ws+XEMB);
  k_init<<<dim3((2*PER_+255)/256), dim3(256), 0, stream>>>(
      mW1in, mb1in, mW2in, mb2in, ws+PW1, ws+PB1, ws+PW2T, ws+PB2);

  for (int s = 0; s < NSEG_; s++) {
    const float* segA = ws + XEMB + (size_t)s*SEG_*D_;
    // h = mlp(p, l2n(seg @ Wq + bq))
    gemm(segA, Wq, bq, ws+Q1, SEG_, D_, D_, (long)N_*D_, 0, (long)SEG_*D_, 0, B_, 0, 0, stream);
    k_l2n<<<dim3(B_*SEG_), dim3(256), 0, stream>>>(ws+Q1);
    gemm(ws+Q1, ws+PW1, ws+PB1, ws+AH, SEG_, W_, D_, (long)SEG_*D_, (long)D_*W_, (long)SEG_*W_, W_, B_, 0, 1, stream);
    gemm(ws+AH, ws+PW2T, ws+PB2, ws+HBUF, SEG_, D_, W_, (long)SEG_*W_, (long)D_*W_, (long)SEG_*D_, D_, B_, 1, 0, stream);
    // combined -> qkv -> attention -> seg_out
    k_concat<<<dim3(T_, B_), dim3(256), 0, stream>>>(pers, ws+HBUF, ws+XEMB, s, ws+COMB);
    gemm(ws+COMB, aiw, aib, ws+QKV, B_*T_, 3*D_, D_, 0, 0, 0, 0, 1, 0, 0, stream);
    k_attn<<<dim3(8, NH_, B_), dim3(256), 0, stream>>>(ws+QKV, ws+ATTN);
    gemm(ws+ATTN, aow, aob, ws+SEGO, B_*SEG_, D_, D_, 0, 0, 0, 0, 1, 0, 0, stream);
    // K = l2n(seg_out @ Wk + bk), V = seg_out @ Wv + bv
    gemm(ws+SEGO, Wk, bk, ws+KM, B_*SEG_, D_, D_, 0, 0, 0, 0, 1, 0, 0, stream);
    k_l2n<<<dim3(B_*SEG_), dim3(256), 0, stream>>>(ws+KM);
    gemm(ws+SEGO, Wv, bv, ws+VM, B_*SEG_, D_, D_, 0, 0, 0, 0, 1, 0, 0, stream);
    // sequential token scan (128 steps + final update)
    for (int t = 0; t <= SEG_; t++) {
      k_tokA<<<dim3(64), dim3(256), 0, stream>>>(
          ws+PW1, ws+PB1, ws+MW1, ws+MB1, ws+KM, ws+Z1FG, ws+DZ1P, ws+Z1P, t);
      k_tokB<<<dim3(64), dim3(256), 0, stream>>>(
          ws+PW2T, ws+PB2, ws+MW2T, ws+MB2, ws+PB1, ws+VM, ws+Z1P,
          ws+DZ1P, ws+A1G, ws+Z1FG, ws+EG, t);
    }
    // mem_out = mlp(p, l2n(seg_out @ Wq + bq)); outs = seg_out * mem_out
    gemm(ws+SEGO, Wq, bq, ws+Q1, B_*SEG_, D_, D_, 0, 0, 0, 0, 1, 0, 0, stream);
    k_l2n<<<dim3(B_*SEG_), dim3(256), 0, stream>>>(ws+Q1);
    gemm(ws+Q1, ws+PW1, ws+PB1, ws+AH, SEG_, W_, D_, (long)SEG_*D_, (long)D_*W_, (long)SEG_*W_, W_, B_, 0, 1, stream);
    gemm(ws+AH, ws+PW2T, ws+PB2, ws+MEMO, SEG_, D_, W_, (long)SEG_*W_, (long)D_*W_, (long)SEG_*D_, D_, B_, 1, 0, stream);
    k_mul<<<dim3(SEG_, B_), dim3(256), 0, stream>>>(ws+SEGO, ws+MEMO, ws+OUTS, s);
  }
  // head: out = full @ head_w + head_b
  gemm(ws+OUTS, headw, headb, out, B_*N_, V_, D_, 0, 0, 0, 0, 1, 0, 0, stream);
}